// Round 4
// baseline (185.046 us; speedup 1.0000x reference)
//
#include <hip/hip_runtime.h>

namespace {

typedef __attribute__((ext_vector_type(4))) float f32x4;
typedef __attribute__((ext_vector_type(8))) short bf16x8;

constexpr int WFRAG_ELEMS = 24 * 8 * 64 * 8;          // 98304 bf16
constexpr int WFRAG_BYTES = WFRAG_ELEMS * 2;          // 196608
constexpr int BIAS_ELEMS  = 8 * 64 * 64;              // 32768 f32
constexpr size_t QKF_OFF  = (size_t)WFRAG_BYTES + (size_t)BIAS_ELEMS * 4;  // 327680
// per (window,head): [2 qk][4 tile][48 lane][8] bf16 = 3072 elems = 6144 B
constexpr size_t QKF_ELEMS_PER_BW = 8 * 3072;          // per (b,win)
constexpr size_t QKF_BYTES = (size_t)2048 * QKF_ELEMS_PER_BW * 2;  // 100663296
constexpr size_t WS_SPLIT = QKF_OFF + QKF_BYTES;
constexpr size_t WS_FUSED = 0;  // fused fallback needs no ws

// LDS layout (bytes). XS is dead after the projection MFMAs; CB overlays it.
constexpr int TOK_OFF = 0;                 // 64 ints (dead after staging)
constexpr int XS_OFF  = 256;               // [4 m][8 kk][64 lane][8] bf16 = 32768 B
constexpr int CB_OFF  = 0;                 // 64 x 384 bf16, XOR-swizzled = 49152 B
constexpr int LDS_TOTAL = 49152;           // -> 3 blocks/CU

__device__ __forceinline__ unsigned short f2bf(float f) {
  unsigned u = __float_as_uint(f);
  u += 0x7fffu + ((u >> 16) & 1u);   // RNE
  return (unsigned short)(u >> 16);
}

// byte offset of C[row][col] (bf16) with 16B-slot XOR swizzle
__device__ __forceinline__ int cb_addr(int row, int col) {
  const int slot = (col >> 3) ^ (row & 7);
  return CB_OFF + row * 768 + (slot << 4) + ((col & 7) << 1);
}

__global__ void prep(const float* __restrict__ w_in,
                     const float* __restrict__ btab,
                     const int*   __restrict__ rpidx,
                     unsigned short* __restrict__ wfrag,
                     float* __restrict__ biasx) {
  const int t = blockIdx.x * 256 + threadIdx.x;
  if (t < WFRAG_ELEMS) {
    const int j    = t & 7;
    const int lane = (t >> 3) & 63;
    const int kk   = (t >> 9) & 7;
    const int nt   = t >> 12;
    const int k    = kk * 32 + (lane >> 4) * 8 + j;
    const int col  = nt * 16 + (lane & 15);
    wfrag[t] = f2bf(w_in[k * 384 + col]);
  } else if (t < WFRAG_ELEMS + BIAS_ELEMS) {
    const int o = t - WFRAG_ELEMS;
    const int j = o & 63, i = (o >> 6) & 63, h = o >> 12;
    biasx[o] = btab[rpidx[i * 64 + j] * 8 + h];
  }
}

// ---------------- shared device helpers for proj phases -------------------

// K1: gather + projection; emit per-head Q/K MFMA fragments to ws.
__global__ __launch_bounds__(256, 3)
void proj_frags(const float* __restrict__ x,
                const int*   __restrict__ reidx,
                const float* __restrict__ b_in,
                const unsigned short* __restrict__ wfrag,
                unsigned short* __restrict__ qkf) {
  extern __shared__ char lds[];
  int* tok           = reinterpret_cast<int*>(lds + TOK_OFF);
  unsigned short* xs = reinterpret_cast<unsigned short*>(lds + XS_OFF);

  const int tid  = threadIdx.x;
  const int b    = blockIdx.x >> 10;
  const int win  = blockIdx.x & 1023;
  const int wh   = win >> 5, ww = win & 31;
  const int wave = tid >> 6, lane = tid & 63;
  const int l15  = lane & 15, q = lane >> 4;

  if (tid < 64)
    tok[tid] = reidx[(wh * 8 + (tid >> 3)) * 256 + ww * 8 + (tid & 7)];
  __syncthreads();

  // stage gathered x rows as MFMA A-fragments
  {
    const int srow = tid >> 2;
    const int part = tid & 3;
    const int sm_t = srow >> 4, sr15 = srow & 15;
    const int swr  = sr15 ^ (part << 1);
    const float* xrow = x + ((size_t)b * 65536 + (size_t)tok[srow]) * 256;
#pragma unroll
    for (int hf = 0; hf < 2; ++hf) {
      const float* src = xrow + hf * 128 + part * 32;
#pragma unroll
      for (int g = 0; g < 4; ++g) {
        const float4 v0 = *reinterpret_cast<const float4*>(src + g * 8);
        const float4 v1 = *reinterpret_cast<const float4*>(src + g * 8 + 4);
        bf16x8 u;
        u[0] = (short)f2bf(v0.x); u[1] = (short)f2bf(v0.y);
        u[2] = (short)f2bf(v0.z); u[3] = (short)f2bf(v0.w);
        u[4] = (short)f2bf(v1.x); u[5] = (short)f2bf(v1.y);
        u[6] = (short)f2bf(v1.z); u[7] = (short)f2bf(v1.w);
        *reinterpret_cast<bf16x8*>(
            xs + ((sm_t * 8 + hf * 4 + part) * 64 + g * 16 + swr) * 8) = u;
      }
    }
  }
  __syncthreads();

  // projection: C[64][384] = X[64][256] * W
  f32x4 acc[6][4];
#pragma unroll
  for (int n = 0; n < 6; ++n)
#pragma unroll
    for (int m = 0; m < 4; ++m) acc[n][m] = (f32x4){0.f, 0.f, 0.f, 0.f};

#pragma unroll
  for (int kk = 0; kk < 8; ++kk) {
    const int rlane = q * 16 + (l15 ^ ((kk & 3) << 1));
    bf16x8 af[4];
#pragma unroll
    for (int m = 0; m < 4; ++m)
      af[m] = *reinterpret_cast<const bf16x8*>(xs + ((m * 8 + kk) * 64 + rlane) * 8);
#pragma unroll
    for (int n = 0; n < 6; ++n) {
      const bf16x8 bfr = *reinterpret_cast<const bf16x8*>(
          wfrag + (((wave * 6 + n) * 8 + kk) * 64 + lane) * 8);
#pragma unroll
      for (int m = 0; m < 4; ++m)
        acc[n][m] = __builtin_amdgcn_mfma_f32_16x16x32_bf16(af[m], bfr, acc[n][m], 0, 0, 0);
    }
  }
  __syncthreads();   // xs dead; CB overlays it

  // write C (+bias) to swizzled LDS buffer as bf16
#pragma unroll
  for (int n = 0; n < 6; ++n) {
    const int colg = wave * 96 + n * 16 + l15;
    const float bv = b_in[colg];
#pragma unroll
    for (int m = 0; m < 4; ++m)
#pragma unroll
      for (int r = 0; r < 4; ++r) {
        const int row = m * 16 + q * 4 + r;
        *reinterpret_cast<unsigned short*>(lds + cb_addr(row, colg)) =
            f2bf(acc[n][m][r] + bv);
      }
  }
  __syncthreads();

  // extract per-head Q/K fragments, store to ws (contiguous 768B per tile)
  if (lane < 48) {
#pragma unroll
    for (int hh = 0; hh < 2; ++hh) {
      const int h = wave * 2 + hh;
      unsigned short* dst = qkf + ((size_t)blockIdx.x * 8 + h) * 3072;
#pragma unroll
      for (int mi = 0; mi < 4; ++mi) {
        const bf16x8 v = *reinterpret_cast<const bf16x8*>(
            lds + cb_addr(mi * 16 + l15, h * 24 + q * 8));
        *reinterpret_cast<bf16x8*>(dst + (mi * 48 + lane) * 8) = v;
      }
#pragma unroll
      for (int ni = 0; ni < 4; ++ni) {
        const bf16x8 v = *reinterpret_cast<const bf16x8*>(
            lds + cb_addr(ni * 16 + l15, 192 + h * 24 + q * 8));
        *reinterpret_cast<bf16x8*>(dst + 1536 + (ni * 48 + lane) * 8) = v;
      }
    }
  }
}

// K2: zero-LDS, zero-barrier score/softmax streamer.
__global__ __launch_bounds__(256)
void scores_k(const unsigned short* __restrict__ qkf,
              const float* __restrict__ biasx,
              float* __restrict__ out) {
  const int tid  = threadIdx.x;
  const int bwi  = blockIdx.x;
  const int b    = bwi >> 10;
  const int win  = bwi & 1023;
  const int wave = tid >> 6, lane = tid & 63;
  const int l15  = lane & 15, q = lane >> 4;

  const bf16x8 vz = {0, 0, 0, 0, 0, 0, 0, 0};
  const f32x4 cz = {0.f, 0.f, 0.f, 0.f};

  for (int hh = 0; hh < 2; ++hh) {
    const int h = wave * 2 + hh;
    const unsigned short* src = qkf + ((size_t)bwi * 8 + h) * 3072;

    bf16x8 aq[4], bk[4];
#pragma unroll
    for (int mi = 0; mi < 4; ++mi)
      aq[mi] = (lane < 48)
                   ? *reinterpret_cast<const bf16x8*>(src + (mi * 48 + lane) * 8)
                   : vz;
#pragma unroll
    for (int ni = 0; ni < 4; ++ni)
      bk[ni] = (lane < 48)
                   ? *reinterpret_cast<const bf16x8*>(src + 1536 + (ni * 48 + lane) * 8)
                   : vz;

    // s[ai][bi] = Sᵀ tile: rows kt (ai*16 + q*4 + r), cols qt (bi*16 + l15)
    f32x4 s[4][4];
#pragma unroll
    for (int ai = 0; ai < 4; ++ai)
#pragma unroll
      for (int bi = 0; bi < 4; ++bi)
        s[ai][bi] = __builtin_amdgcn_mfma_f32_16x16x32_bf16(bk[ai], aq[bi], cz, 0, 0, 0);

    const size_t obase = (((size_t)h * 2 + b) * 1024 + win) * 4096;

#pragma unroll
    for (int bi = 0; bi < 4; ++bi) {
      const int qt = bi * 16 + l15;
      f32x4 p[4];
#pragma unroll
      for (int ai = 0; ai < 4; ++ai) {
        const f32x4 bb = *reinterpret_cast<const f32x4*>(
            biasx + ((size_t)(h * 64 + qt)) * 64 + ai * 16 + q * 4);
        p[ai] = s[ai][bi] + bb;
      }
      float mx = fmaxf(fmaxf(p[0][0], p[0][1]), fmaxf(p[0][2], p[0][3]));
#pragma unroll
      for (int ai = 1; ai < 4; ++ai)
        mx = fmaxf(mx, fmaxf(fmaxf(p[ai][0], p[ai][1]), fmaxf(p[ai][2], p[ai][3])));
      mx = fmaxf(mx, __shfl_xor(mx, 16));
      mx = fmaxf(mx, __shfl_xor(mx, 32));

      float sum = 0.f;
#pragma unroll
      for (int ai = 0; ai < 4; ++ai)
#pragma unroll
        for (int r = 0; r < 4; ++r) {
          p[ai][r] = __expf(p[ai][r] - mx);
          sum += p[ai][r];
        }
      sum += __shfl_xor(sum, 16);
      sum += __shfl_xor(sum, 32);
      const float inv = __builtin_amdgcn_rcpf(sum);

      float* op = out + obase + (size_t)qt * 64 + q * 4;
#pragma unroll
      for (int ai = 0; ai < 4; ++ai) {
        f32x4 o = p[ai] * inv;
        *reinterpret_cast<f32x4*>(op + ai * 16) = o;
      }
    }
  }
}

// ---------------- fallback: round-3 fused kernel (no ws needed) -----------
__global__ __launch_bounds__(256, 3)
void fused_full(const float* __restrict__ x,
                const int*   __restrict__ reidx,
                const float* __restrict__ w_in,
                const float* __restrict__ b_in,
                const float* __restrict__ btab,
                const int*   __restrict__ rpidx,
                float*       __restrict__ out) {
  extern __shared__ char lds[];
  int* tok           = reinterpret_cast<int*>(lds + TOK_OFF);
  unsigned short* xs = reinterpret_cast<unsigned short*>(lds + XS_OFF);

  const int tid  = threadIdx.x;
  const int b    = blockIdx.x >> 10;
  const int win  = blockIdx.x & 1023;
  const int wh   = win >> 5, ww = win & 31;
  const int wave = tid >> 6, lane = tid & 63;
  const int l15  = lane & 15, q = lane >> 4;

  if (tid < 64)
    tok[tid] = reidx[(wh * 8 + (tid >> 3)) * 256 + ww * 8 + (tid & 7)];
  __syncthreads();

  {
    const int srow = tid >> 2;
    const int part = tid & 3;
    const int sm_t = srow >> 4, sr15 = srow & 15;
    const int swr  = sr15 ^ (part << 1);
    const float* xrow = x + ((size_t)b * 65536 + (size_t)tok[srow]) * 256;
#pragma unroll
    for (int hf = 0; hf < 2; ++hf) {
      const float* src = xrow + hf * 128 + part * 32;
#pragma unroll
      for (int g = 0; g < 4; ++g) {
        const float4 v0 = *reinterpret_cast<const float4*>(src + g * 8);
        const float4 v1 = *reinterpret_cast<const float4*>(src + g * 8 + 4);
        bf16x8 u;
        u[0] = (short)f2bf(v0.x); u[1] = (short)f2bf(v0.y);
        u[2] = (short)f2bf(v0.z); u[3] = (short)f2bf(v0.w);
        u[4] = (short)f2bf(v1.x); u[5] = (short)f2bf(v1.y);
        u[6] = (short)f2bf(v1.z); u[7] = (short)f2bf(v1.w);
        *reinterpret_cast<bf16x8*>(
            xs + ((sm_t * 8 + hf * 4 + part) * 64 + g * 16 + swr) * 8) = u;
      }
    }
  }
  __syncthreads();

  f32x4 acc[6][4];
#pragma unroll
  for (int n = 0; n < 6; ++n)
#pragma unroll
    for (int m = 0; m < 4; ++m) acc[n][m] = (f32x4){0.f, 0.f, 0.f, 0.f};

#pragma unroll
  for (int kk = 0; kk < 8; ++kk) {
    const int rlane = q * 16 + (l15 ^ ((kk & 3) << 1));
    bf16x8 af[4];
#pragma unroll
    for (int m = 0; m < 4; ++m)
      af[m] = *reinterpret_cast<const bf16x8*>(xs + ((m * 8 + kk) * 64 + rlane) * 8);
#pragma unroll
    for (int n = 0; n < 6; ++n) {
      const int colg = wave * 96 + n * 16 + l15;
      bf16x8 bfr;
#pragma unroll
      for (int jj = 0; jj < 8; ++jj)
        bfr[jj] = (short)f2bf(w_in[(kk * 32 + q * 8 + jj) * 384 + colg]);
#pragma unroll
      for (int m = 0; m < 4; ++m)
        acc[n][m] = __builtin_amdgcn_mfma_f32_16x16x32_bf16(af[m], bfr, acc[n][m], 0, 0, 0);
    }
  }
  __syncthreads();

#pragma unroll
  for (int n = 0; n < 6; ++n) {
    const int colg = wave * 96 + n * 16 + l15;
    const float bv = b_in[colg];
#pragma unroll
    for (int m = 0; m < 4; ++m)
#pragma unroll
      for (int r = 0; r < 4; ++r) {
        const int row = m * 16 + q * 4 + r;
        *reinterpret_cast<unsigned short*>(lds + cb_addr(row, colg)) =
            f2bf(acc[n][m][r] + bv);
      }
  }
  __syncthreads();

  const bf16x8 vz = {0, 0, 0, 0, 0, 0, 0, 0};
  const f32x4 cz = {0.f, 0.f, 0.f, 0.f};

  for (int hh = 0; hh < 2; ++hh) {
    const int h = wave * 2 + hh;

    bf16x8 aq[4], bk[4];
#pragma unroll
    for (int mi = 0; mi < 4; ++mi)
      aq[mi] = (lane < 48)
                   ? *reinterpret_cast<const bf16x8*>(lds + cb_addr(mi * 16 + l15, h * 24 + q * 8))
                   : vz;
#pragma unroll
    for (int ni = 0; ni < 4; ++ni)
      bk[ni] = (lane < 48)
                   ? *reinterpret_cast<const bf16x8*>(lds + cb_addr(ni * 16 + l15, 192 + h * 24 + q * 8))
                   : vz;

    f32x4 s[4][4];
#pragma unroll
    for (int ai = 0; ai < 4; ++ai)
#pragma unroll
      for (int bi = 0; bi < 4; ++bi)
        s[ai][bi] = __builtin_amdgcn_mfma_f32_16x16x32_bf16(bk[ai], aq[bi], cz, 0, 0, 0);

    const size_t obase = (((size_t)h * 2 + b) * 1024 + win) * 4096;

#pragma unroll
    for (int bi = 0; bi < 4; ++bi) {
      const int qt = bi * 16 + l15;
      f32x4 p[4];
#pragma unroll
      for (int ai = 0; ai < 4; ++ai) {
#pragma unroll
        for (int r = 0; r < 4; ++r)
          p[ai][r] = s[ai][bi][r] +
                     btab[rpidx[qt * 64 + ai * 16 + q * 4 + r] * 8 + h];
      }
      float mx = fmaxf(fmaxf(p[0][0], p[0][1]), fmaxf(p[0][2], p[0][3]));
#pragma unroll
      for (int ai = 1; ai < 4; ++ai)
        mx = fmaxf(mx, fmaxf(fmaxf(p[ai][0], p[ai][1]), fmaxf(p[ai][2], p[ai][3])));
      mx = fmaxf(mx, __shfl_xor(mx, 16));
      mx = fmaxf(mx, __shfl_xor(mx, 32));

      float sum = 0.f;
#pragma unroll
      for (int ai = 0; ai < 4; ++ai)
#pragma unroll
        for (int r = 0; r < 4; ++r) {
          p[ai][r] = __expf(p[ai][r] - mx);
          sum += p[ai][r];
        }
      sum += __shfl_xor(sum, 16);
      sum += __shfl_xor(sum, 32);
      const float inv = __builtin_amdgcn_rcpf(sum);

      float* op = out + obase + (size_t)qt * 64 + q * 4;
#pragma unroll
      for (int ai = 0; ai < 4; ++ai) {
        f32x4 o = p[ai] * inv;
        *reinterpret_cast<f32x4*>(op + ai * 16) = o;
      }
    }
  }
}

}  // namespace

extern "C" void kernel_launch(void* const* d_in, const int* in_sizes, int n_in,
                              void* d_out, int out_size, void* d_ws, size_t ws_size,
                              hipStream_t stream) {
  const float* x     = (const float*)d_in[0];
  const int*   reidx = (const int*)d_in[1];
  const float* w_in  = (const float*)d_in[2];
  const float* b_in  = (const float*)d_in[3];
  const float* btab  = (const float*)d_in[4];
  const int*   rpidx = (const int*)d_in[5];
  float* out = (float*)d_out;

  if (ws_size >= WS_SPLIT) {
    unsigned short* wfrag = (unsigned short*)d_ws;
    float* biasx = (float*)((char*)d_ws + WFRAG_BYTES);
    unsigned short* qkf = (unsigned short*)((char*)d_ws + QKF_OFF);

    prep<<<dim3((WFRAG_ELEMS + BIAS_ELEMS + 255) / 256), dim3(256), 0, stream>>>(
        w_in, btab, rpidx, wfrag, biasx);
    proj_frags<<<dim3(2048), dim3(256), LDS_TOTAL, stream>>>(
        x, reidx, b_in, wfrag, qkf);
    scores_k<<<dim3(2048), dim3(256), 0, stream>>>(qkf, biasx, out);
  } else {
    fused_full<<<dim3(2048), dim3(256), LDS_TOTAL, stream>>>(
        x, reidx, w_in, b_in, btab, rpidx, out);
  }
}

// Round 5
// 125.165 us; speedup vs baseline: 1.4784x; 1.4784x over previous
//
#include <hip/hip_runtime.h>

namespace {

typedef __attribute__((ext_vector_type(4))) float f32x4;
typedef __attribute__((ext_vector_type(8))) short bf16x8;

constexpr int WFRAG_ELEMS = 24 * 8 * 64 * 8;          // 98304 bf16
constexpr int WFRAG_BYTES = WFRAG_ELEMS * 2;          // 196608
constexpr int BIAS_ELEMS  = 8 * 64 * 64;              // 32768 f32
constexpr size_t WS_NEEDED = (size_t)WFRAG_BYTES + (size_t)BIAS_ELEMS * 4;  // 327680

// LDS layout (bytes). XS dead after proj; CB overlays it. PB = per-wave
// 4KB store-bounce tiles (wave-local, no barrier needed).
constexpr int TOK_OFF = 0;                 // 64 ints (dead after staging)
constexpr int XS_OFF  = 256;               // [4 m][8 kk][64 lane][8] bf16 = 32768 B
constexpr int CB_OFF  = 0;                 // 64 x 384 bf16, XOR-swizzled = 49152 B
constexpr int PB_OFF  = 49152;             // 4 waves x 4096 B
constexpr int LDS_TOTAL = 65536;           // -> 2 blocks/CU

__device__ __forceinline__ unsigned short f2bf(float f) {
  unsigned u = __float_as_uint(f);
  u += 0x7fffu + ((u >> 16) & 1u);   // RNE
  return (unsigned short)(u >> 16);
}

// byte offset of C[row][col] (bf16) with 16B-slot XOR swizzle
__device__ __forceinline__ int cb_addr(int row, int col) {
  const int slot = (col >> 3) ^ (row & 7);
  return CB_OFF + row * 768 + (slot << 4) + ((col & 7) << 1);
}

// bounce-tile slot: P[row16][kt], 16B slot = ((kt>>2) ^ row16) & 15
__device__ __forceinline__ int pb_addr(int wavebase, int row16, int ktq) {
  return wavebase + row16 * 256 + (((ktq ^ row16) & 15) << 4);
}

__global__ void prep(const float* __restrict__ w_in,
                     const float* __restrict__ btab,
                     const int*   __restrict__ rpidx,
                     unsigned short* __restrict__ wfrag,
                     float* __restrict__ biasx) {
  const int t = blockIdx.x * 256 + threadIdx.x;
  if (t < WFRAG_ELEMS) {
    const int j    = t & 7;
    const int lane = (t >> 3) & 63;
    const int kk   = (t >> 9) & 7;
    const int nt   = t >> 12;
    const int k    = kk * 32 + (lane >> 4) * 8 + j;
    const int col  = nt * 16 + (lane & 15);
    wfrag[t] = f2bf(w_in[k * 384 + col]);
  } else if (t < WFRAG_ELEMS + BIAS_ELEMS) {
    const int o = t - WFRAG_ELEMS;
    const int j = o & 63, i = (o >> 6) & 63, h = o >> 12;
    biasx[o] = btab[rpidx[i * 64 + j] * 8 + h];
  }
}

template <bool USE_WS>
__global__ __launch_bounds__(256, 2)
void fused_mhaw(const float* __restrict__ x,
                const int*   __restrict__ reidx,
                const float* __restrict__ w_in,
                const float* __restrict__ b_in,
                const float* __restrict__ btab,
                const int*   __restrict__ rpidx,
                const unsigned short* __restrict__ wfrag,
                const float* __restrict__ biasx,
                float*       __restrict__ out) {
  extern __shared__ char lds[];
  int* tok           = reinterpret_cast<int*>(lds + TOK_OFF);
  unsigned short* xs = reinterpret_cast<unsigned short*>(lds + XS_OFF);

  const int tid  = threadIdx.x;
  const int b    = blockIdx.x >> 10;
  const int win  = blockIdx.x & 1023;
  const int wh   = win >> 5, ww = win & 31;
  const int wave = tid >> 6, lane = tid & 63;
  const int l15  = lane & 15, q = lane >> 4;
  const int pbase = PB_OFF + wave * 4096;

  if (tid < 64)
    tok[tid] = reidx[(wh * 8 + (tid >> 3)) * 256 + ww * 8 + (tid & 7)];
  __syncthreads();

  // ---------------- stage gathered x rows as MFMA A-fragments --------------
  {
    const int srow = tid >> 2;       // token row this thread stages
    const int part = tid & 3;        // 32-float chunk within each K-half
    const int sm_t = srow >> 4, sr15 = srow & 15;
    const int swr  = sr15 ^ (part << 1);   // break 8-way write conflict
    const float* xrow = x + ((size_t)b * 65536 + (size_t)tok[srow]) * 256;
#pragma unroll
    for (int hf = 0; hf < 2; ++hf) {
      const float* src = xrow + hf * 128 + part * 32;
#pragma unroll
      for (int g = 0; g < 4; ++g) {
        const float4 v0 = *reinterpret_cast<const float4*>(src + g * 8);
        const float4 v1 = *reinterpret_cast<const float4*>(src + g * 8 + 4);
        bf16x8 u;
        u[0] = (short)f2bf(v0.x); u[1] = (short)f2bf(v0.y);
        u[2] = (short)f2bf(v0.z); u[3] = (short)f2bf(v0.w);
        u[4] = (short)f2bf(v1.x); u[5] = (short)f2bf(v1.y);
        u[6] = (short)f2bf(v1.z); u[7] = (short)f2bf(v1.w);
        *reinterpret_cast<bf16x8*>(
            xs + ((sm_t * 8 + hf * 4 + part) * 64 + g * 16 + swr) * 8) = u;
      }
    }
  }
  __syncthreads();

  // ---------------- projection: C[64][384] = X[64][256] * W ----------------
  f32x4 acc[6][4];
#pragma unroll
  for (int n = 0; n < 6; ++n)
#pragma unroll
    for (int m = 0; m < 4; ++m) acc[n][m] = (f32x4){0.f, 0.f, 0.f, 0.f};

#pragma unroll
  for (int kk = 0; kk < 8; ++kk) {
    const int rlane = q * 16 + (l15 ^ ((kk & 3) << 1));   // un-swizzle
    bf16x8 af[4];
#pragma unroll
    for (int m = 0; m < 4; ++m)
      af[m] = *reinterpret_cast<const bf16x8*>(xs + ((m * 8 + kk) * 64 + rlane) * 8);
#pragma unroll
    for (int n = 0; n < 6; ++n) {
      bf16x8 bfr;
      if (USE_WS) {
        bfr = *reinterpret_cast<const bf16x8*>(
            wfrag + (((wave * 6 + n) * 8 + kk) * 64 + lane) * 8);
      } else {
        const int colg = wave * 96 + n * 16 + l15;
#pragma unroll
        for (int jj = 0; jj < 8; ++jj)
          bfr[jj] = (short)f2bf(w_in[(kk * 32 + q * 8 + jj) * 384 + colg]);
      }
#pragma unroll
      for (int m = 0; m < 4; ++m)
        acc[n][m] = __builtin_amdgcn_mfma_f32_16x16x32_bf16(af[m], bfr, acc[n][m], 0, 0, 0);
    }
  }
  __syncthreads();   // xs dead; CB overlays it

  // write C (+bias) to swizzled LDS buffer as bf16
#pragma unroll
  for (int n = 0; n < 6; ++n) {
    const int colg = wave * 96 + n * 16 + l15;
    const float bv = b_in[colg];
#pragma unroll
    for (int m = 0; m < 4; ++m)
#pragma unroll
      for (int r = 0; r < 4; ++r) {
        const int row = m * 16 + q * 4 + r;
        *reinterpret_cast<unsigned short*>(lds + cb_addr(row, colg)) =
            f2bf(acc[n][m][r] + bv);
      }
  }
  __syncthreads();

  // ---------------- per-head K·Qᵀ (=Sᵀ) + bias + softmax -------------------
  const bf16x8 vz = {0, 0, 0, 0, 0, 0, 0, 0};
  const f32x4 cz = {0.f, 0.f, 0.f, 0.f};

  for (int hh = 0; hh < 2; ++hh) {
    const int h = wave * 2 + hh;

    bf16x8 aq[4], bk[4];
#pragma unroll
    for (int mi = 0; mi < 4; ++mi)
      aq[mi] = (lane < 48)
                   ? *reinterpret_cast<const bf16x8*>(lds + cb_addr(mi * 16 + l15, h * 24 + q * 8))
                   : vz;
#pragma unroll
    for (int ni = 0; ni < 4; ++ni)
      bk[ni] = (lane < 48)
                   ? *reinterpret_cast<const bf16x8*>(lds + cb_addr(ni * 16 + l15, 192 + h * 24 + q * 8))
                   : vz;

    // s[ai][bi] = tile of Sᵀ: rows kt (ai*16 + q*4 + r), cols qt (bi*16 + l15)
    f32x4 s[4][4];
#pragma unroll
    for (int ai = 0; ai < 4; ++ai)
#pragma unroll
      for (int bi = 0; bi < 4; ++bi)
        s[ai][bi] = __builtin_amdgcn_mfma_f32_16x16x32_bf16(bk[ai], aq[bi], cz, 0, 0, 0);

    const size_t obase = (((size_t)h * 2 + b) * 1024 + win) * 4096;

#pragma unroll
    for (int bi = 0; bi < 4; ++bi) {
      const int qt = bi * 16 + l15;           // query row this lane owns
      f32x4 p[4];
#pragma unroll
      for (int ai = 0; ai < 4; ++ai) {
        if (USE_WS) {
          const f32x4 bb = *reinterpret_cast<const f32x4*>(
              biasx + ((size_t)(h * 64 + qt)) * 64 + ai * 16 + q * 4);
          p[ai] = s[ai][bi] + bb;
        } else {
#pragma unroll
          for (int r = 0; r < 4; ++r)
            p[ai][r] = s[ai][bi][r] +
                       btab[rpidx[qt * 64 + ai * 16 + q * 4 + r] * 8 + h];
        }
      }
      float mx = fmaxf(fmaxf(p[0][0], p[0][1]), fmaxf(p[0][2], p[0][3]));
#pragma unroll
      for (int ai = 1; ai < 4; ++ai)
        mx = fmaxf(mx, fmaxf(fmaxf(p[ai][0], p[ai][1]), fmaxf(p[ai][2], p[ai][3])));
      mx = fmaxf(mx, __shfl_xor(mx, 16));
      mx = fmaxf(mx, __shfl_xor(mx, 32));

      float sum = 0.f;
#pragma unroll
      for (int ai = 0; ai < 4; ++ai)
#pragma unroll
        for (int r = 0; r < 4; ++r) {
          p[ai][r] = __expf(p[ai][r] - mx);
          sum += p[ai][r];
        }
      sum += __shfl_xor(sum, 16);
      sum += __shfl_xor(sum, 32);
      const float inv = __builtin_amdgcn_rcpf(sum);

      // ---- store via per-wave LDS bounce: 1KB contiguous per instruction --
      // write P[row16 = l15][kt = ai*16 + q*4 .. +3]
#pragma unroll
      for (int ai = 0; ai < 4; ++ai) {
        const f32x4 o = p[ai] * inv;
        *reinterpret_cast<f32x4*>(lds + pb_addr(pbase, l15, ai * 4 + q)) = o;
      }
      // read P[row16 = i*4 + q][kt = l15*4 .. +3], store 4 rows = 1KB / instr
#pragma unroll
      for (int i = 0; i < 4; ++i) {
        const int row16 = i * 4 + q;
        const f32x4 v = *reinterpret_cast<const f32x4*>(
            lds + pb_addr(pbase, row16, l15));
        __builtin_nontemporal_store(
            v, reinterpret_cast<f32x4*>(
                   out + obase + (size_t)(bi * 16 + row16) * 64 + l15 * 4));
      }
    }
  }
}

}  // namespace

extern "C" void kernel_launch(void* const* d_in, const int* in_sizes, int n_in,
                              void* d_out, int out_size, void* d_ws, size_t ws_size,
                              hipStream_t stream) {
  const float* x     = (const float*)d_in[0];
  const int*   reidx = (const int*)d_in[1];
  const float* w_in  = (const float*)d_in[2];
  const float* b_in  = (const float*)d_in[3];
  const float* btab  = (const float*)d_in[4];
  const int*   rpidx = (const int*)d_in[5];
  float* out = (float*)d_out;

  const bool use_ws = ws_size >= WS_NEEDED;
  unsigned short* wfrag = (unsigned short*)d_ws;
  float* biasx = (float*)((char*)d_ws + WFRAG_BYTES);

  if (use_ws) {
    prep<<<dim3((WFRAG_ELEMS + BIAS_ELEMS + 255) / 256), dim3(256), 0, stream>>>(
        w_in, btab, rpidx, wfrag, biasx);
    fused_mhaw<true><<<dim3(2048), dim3(256), LDS_TOTAL, stream>>>(
        x, reidx, w_in, b_in, btab, rpidx, wfrag, biasx, out);
  } else {
    fused_mhaw<false><<<dim3(2048), dim3(256), LDS_TOTAL, stream>>>(
        x, reidx, w_in, b_in, btab, rpidx, nullptr, nullptr, out);
  }
}

// Round 6
// 110.323 us; speedup vs baseline: 1.6773x; 1.1345x over previous
//
#include <hip/hip_runtime.h>

namespace {

typedef __attribute__((ext_vector_type(4))) float f32x4;
typedef __attribute__((ext_vector_type(8))) short bf16x8;

constexpr int WFRAG_ELEMS = 24 * 8 * 64 * 8;          // 98304 bf16
constexpr int WFRAG_BYTES = WFRAG_ELEMS * 2;          // 196608
constexpr int BIAS_ELEMS  = 8 * 64 * 64;              // 32768 f32
constexpr size_t WS_NEEDED = (size_t)WFRAG_BYTES + (size_t)BIAS_ELEMS * 4;  // 327680

// LDS layout (bytes), all overlaid in one 48KB arena:
//  - XS [0..32768): x staged as MFMA A-fragments (dead after proj MFMAs)
//  - CB [0..49152): C = proj+bias, bf16, XOR-swizzled (written after XS dies;
//                   dead after score-phase fragment loads)
//  - PB [wave*4096 .. +4096): per-wave f32 store-bounce tiles (used only
//                   after the frags-loaded barrier, when CB is dead)
constexpr int XS_OFF    = 0;
constexpr int CB_OFF    = 0;
constexpr int PB_STRIDE = 4096;
constexpr int LDS_TOTAL = 49152;           // -> 3 blocks/CU

__device__ __forceinline__ unsigned short f2bf(float f) {
  unsigned u = __float_as_uint(f);
  u += 0x7fffu + ((u >> 16) & 1u);   // RNE
  return (unsigned short)(u >> 16);
}

// byte offset of C[row][col] (bf16) with 16B-slot XOR swizzle
__device__ __forceinline__ int cb_addr(int row, int col) {
  const int slot = (col >> 3) ^ (row & 7);
  return CB_OFF + row * 768 + (slot << 4) + ((col & 7) << 1);
}

// bounce-tile slot: P[row16][kt], 16B slot = (ktq ^ row16) & 15
__device__ __forceinline__ int pb_addr(int wavebase, int row16, int ktq) {
  return wavebase + row16 * 256 + (((ktq ^ row16) & 15) << 4);
}

__global__ void prep(const float* __restrict__ w_in,
                     const float* __restrict__ btab,
                     const int*   __restrict__ rpidx,
                     unsigned short* __restrict__ wfrag,
                     float* __restrict__ biasx) {
  const int t = blockIdx.x * 256 + threadIdx.x;
  if (t < WFRAG_ELEMS) {
    const int j    = t & 7;
    const int lane = (t >> 3) & 63;
    const int kk   = (t >> 9) & 7;
    const int nt   = t >> 12;
    const int k    = kk * 32 + (lane >> 4) * 8 + j;
    const int col  = nt * 16 + (lane & 15);
    wfrag[t] = f2bf(w_in[k * 384 + col]);
  } else if (t < WFRAG_ELEMS + BIAS_ELEMS) {
    const int o = t - WFRAG_ELEMS;
    const int j = o & 63, i = (o >> 6) & 63, h = o >> 12;
    biasx[o] = btab[rpidx[i * 64 + j] * 8 + h];
  }
}

template <bool USE_WS>
__global__ __launch_bounds__(256, 3)
void fused_mhaw(const float* __restrict__ x,
                const int*   __restrict__ reidx,
                const float* __restrict__ w_in,
                const float* __restrict__ b_in,
                const float* __restrict__ btab,
                const int*   __restrict__ rpidx,
                const unsigned short* __restrict__ wfrag,
                const float* __restrict__ biasx,
                float*       __restrict__ out) {
  extern __shared__ char lds[];
  unsigned short* xs = reinterpret_cast<unsigned short*>(lds + XS_OFF);

  const int tid  = threadIdx.x;
  const int b    = blockIdx.x >> 10;
  const int win  = blockIdx.x & 1023;
  const int wh   = win >> 5, ww = win & 31;
  const int wave = tid >> 6, lane = tid & 63;
  const int l15  = lane & 15, q = lane >> 4;
  const int pbase = wave * PB_STRIDE;

  // ---------------- stage gathered x rows as MFMA A-fragments --------------
  // (no tok[] LDS buffer: each thread loads its own reidx word directly)
  {
    const int srow = tid >> 2;       // token row this thread stages
    const int part = tid & 3;        // 32-float chunk within each K-half
    const int sm_t = srow >> 4, sr15 = srow & 15;
    const int swr  = sr15 ^ (part << 1);   // break 8-way write conflict
    const int tokv = reidx[(wh * 8 + (srow >> 3)) * 256 + ww * 8 + (srow & 7)];
    const float* xrow = x + ((size_t)b * 65536 + (size_t)tokv) * 256;
#pragma unroll
    for (int hf = 0; hf < 2; ++hf) {
      const float* src = xrow + hf * 128 + part * 32;
#pragma unroll
      for (int g = 0; g < 4; ++g) {
        const float4 v0 = *reinterpret_cast<const float4*>(src + g * 8);
        const float4 v1 = *reinterpret_cast<const float4*>(src + g * 8 + 4);
        bf16x8 u;
        u[0] = (short)f2bf(v0.x); u[1] = (short)f2bf(v0.y);
        u[2] = (short)f2bf(v0.z); u[3] = (short)f2bf(v0.w);
        u[4] = (short)f2bf(v1.x); u[5] = (short)f2bf(v1.y);
        u[6] = (short)f2bf(v1.z); u[7] = (short)f2bf(v1.w);
        *reinterpret_cast<bf16x8*>(
            xs + ((sm_t * 8 + hf * 4 + part) * 64 + g * 16 + swr) * 8) = u;
      }
    }
  }
  __syncthreads();

  // ---------------- projection: C[64][384] = X[64][256] * W ----------------
  f32x4 acc[6][4];
#pragma unroll
  for (int n = 0; n < 6; ++n)
#pragma unroll
    for (int m = 0; m < 4; ++m) acc[n][m] = (f32x4){0.f, 0.f, 0.f, 0.f};

#pragma unroll
  for (int kk = 0; kk < 8; ++kk) {
    const int rlane = q * 16 + (l15 ^ ((kk & 3) << 1));   // un-swizzle
    bf16x8 af[4];
#pragma unroll
    for (int m = 0; m < 4; ++m)
      af[m] = *reinterpret_cast<const bf16x8*>(xs + ((m * 8 + kk) * 64 + rlane) * 8);
#pragma unroll
    for (int n = 0; n < 6; ++n) {
      bf16x8 bfr;
      if (USE_WS) {
        bfr = *reinterpret_cast<const bf16x8*>(
            wfrag + (((wave * 6 + n) * 8 + kk) * 64 + lane) * 8);
      } else {
        const int colg = wave * 96 + n * 16 + l15;
#pragma unroll
        for (int jj = 0; jj < 8; ++jj)
          bfr[jj] = (short)f2bf(w_in[(kk * 32 + q * 8 + jj) * 384 + colg]);
      }
#pragma unroll
      for (int m = 0; m < 4; ++m)
        acc[n][m] = __builtin_amdgcn_mfma_f32_16x16x32_bf16(af[m], bfr, acc[n][m], 0, 0, 0);
    }
  }
  __syncthreads();   // xs dead; CB overlays it

  // write C (+bias) to swizzled LDS buffer as bf16
#pragma unroll
  for (int n = 0; n < 6; ++n) {
    const int colg = wave * 96 + n * 16 + l15;
    const float bv = b_in[colg];
#pragma unroll
    for (int m = 0; m < 4; ++m)
#pragma unroll
      for (int r = 0; r < 4; ++r) {
        const int row = m * 16 + q * 4 + r;
        *reinterpret_cast<unsigned short*>(lds + cb_addr(row, colg)) =
            f2bf(acc[n][m][r] + bv);
      }
  }
  __syncthreads();

  // ---------------- per-head K·Qᵀ (=Sᵀ) + bias + softmax -------------------
  const bf16x8 vz = {0, 0, 0, 0, 0, 0, 0, 0};
  const f32x4 cz = {0.f, 0.f, 0.f, 0.f};
  const int h0 = wave * 2, h1 = h0 + 1;

  auto softmax_store = [&](int h, f32x4 (&s)[4][4]) {
    const size_t obase = (((size_t)h * 2 + b) * 1024 + win) * 4096;
#pragma unroll
    for (int bi = 0; bi < 4; ++bi) {
      const int qt = bi * 16 + l15;           // query row this lane owns
      f32x4 p[4];
#pragma unroll
      for (int ai = 0; ai < 4; ++ai) {
        if (USE_WS) {
          const f32x4 bb = *reinterpret_cast<const f32x4*>(
              biasx + ((size_t)(h * 64 + qt)) * 64 + ai * 16 + q * 4);
          p[ai] = s[ai][bi] + bb;
        } else {
#pragma unroll
          for (int r = 0; r < 4; ++r)
            p[ai][r] = s[ai][bi][r] +
                       btab[rpidx[qt * 64 + ai * 16 + q * 4 + r] * 8 + h];
        }
      }
      float mx = fmaxf(fmaxf(p[0][0], p[0][1]), fmaxf(p[0][2], p[0][3]));
#pragma unroll
      for (int ai = 1; ai < 4; ++ai)
        mx = fmaxf(mx, fmaxf(fmaxf(p[ai][0], p[ai][1]), fmaxf(p[ai][2], p[ai][3])));
      mx = fmaxf(mx, __shfl_xor(mx, 16));
      mx = fmaxf(mx, __shfl_xor(mx, 32));

      float sum = 0.f;
#pragma unroll
      for (int ai = 0; ai < 4; ++ai)
#pragma unroll
        for (int r = 0; r < 4; ++r) {
          p[ai][r] = __expf(p[ai][r] - mx);
          sum += p[ai][r];
        }
      sum += __shfl_xor(sum, 16);
      sum += __shfl_xor(sum, 32);
      const float inv = __builtin_amdgcn_rcpf(sum);

      // store via per-wave LDS bounce: 1KB contiguous per instruction
#pragma unroll
      for (int ai = 0; ai < 4; ++ai) {
        const f32x4 o = p[ai] * inv;
        *reinterpret_cast<f32x4*>(lds + pb_addr(pbase, l15, ai * 4 + q)) = o;
      }
#pragma unroll
      for (int i = 0; i < 4; ++i) {
        const int row16 = i * 4 + q;
        const f32x4 v = *reinterpret_cast<const f32x4*>(
            lds + pb_addr(pbase, row16, l15));
        __builtin_nontemporal_store(
            v, reinterpret_cast<f32x4*>(
                   out + obase + (size_t)(bi * 16 + row16) * 64 + l15 * 4));
      }
    }
  };

  // h0 fragments -> scores (frees frag regs before h1 loads)
  f32x4 s0t[4][4];
  {
    bf16x8 aq[4], bk[4];
#pragma unroll
    for (int mi = 0; mi < 4; ++mi)
      aq[mi] = (lane < 48)
                   ? *reinterpret_cast<const bf16x8*>(lds + cb_addr(mi * 16 + l15, h0 * 24 + q * 8))
                   : vz;
#pragma unroll
    for (int ni = 0; ni < 4; ++ni)
      bk[ni] = (lane < 48)
                   ? *reinterpret_cast<const bf16x8*>(lds + cb_addr(ni * 16 + l15, 192 + h0 * 24 + q * 8))
                   : vz;
#pragma unroll
    for (int ai = 0; ai < 4; ++ai)
#pragma unroll
      for (int bi = 0; bi < 4; ++bi)
        s0t[ai][bi] = __builtin_amdgcn_mfma_f32_16x16x32_bf16(bk[ai], aq[bi], cz, 0, 0, 0);
  }

  // h1 fragments (kept in regs across h0's softmax)
  bf16x8 aq1[4], bk1[4];
#pragma unroll
  for (int mi = 0; mi < 4; ++mi)
    aq1[mi] = (lane < 48)
                  ? *reinterpret_cast<const bf16x8*>(lds + cb_addr(mi * 16 + l15, h1 * 24 + q * 8))
                  : vz;
#pragma unroll
  for (int ni = 0; ni < 4; ++ni)
    bk1[ni] = (lane < 48)
                  ? *reinterpret_cast<const bf16x8*>(lds + cb_addr(ni * 16 + l15, 192 + h1 * 24 + q * 8))
                  : vz;

  __syncthreads();   // all CB reads done block-wide; PB may overwrite CB

  softmax_store(h0, s0t);

  f32x4 s1t[4][4];
#pragma unroll
  for (int ai = 0; ai < 4; ++ai)
#pragma unroll
    for (int bi = 0; bi < 4; ++bi)
      s1t[ai][bi] = __builtin_amdgcn_mfma_f32_16x16x32_bf16(bk1[ai], aq1[bi], cz, 0, 0, 0);

  softmax_store(h1, s1t);
}

}  // namespace

extern "C" void kernel_launch(void* const* d_in, const int* in_sizes, int n_in,
                              void* d_out, int out_size, void* d_ws, size_t ws_size,
                              hipStream_t stream) {
  const float* x     = (const float*)d_in[0];
  const int*   reidx = (const int*)d_in[1];
  const float* w_in  = (const float*)d_in[2];
  const float* b_in  = (const float*)d_in[3];
  const float* btab  = (const float*)d_in[4];
  const int*   rpidx = (const int*)d_in[5];
  float* out = (float*)d_out;

  const bool use_ws = ws_size >= WS_NEEDED;
  unsigned short* wfrag = (unsigned short*)d_ws;
  float* biasx = (float*)((char*)d_ws + WFRAG_BYTES);

  if (use_ws) {
    prep<<<dim3((WFRAG_ELEMS + BIAS_ELEMS + 255) / 256), dim3(256), 0, stream>>>(
        w_in, btab, rpidx, wfrag, biasx);
    fused_mhaw<true><<<dim3(2048), dim3(256), LDS_TOTAL, stream>>>(
        x, reidx, w_in, b_in, btab, rpidx, wfrag, biasx, out);
  } else {
    fused_mhaw<false><<<dim3(2048), dim3(256), LDS_TOTAL, stream>>>(
        x, reidx, w_in, b_in, btab, rpidx, nullptr, nullptr, out);
  }
}